// Round 1
// baseline (1520.246 us; speedup 1.0000x reference)
//
#include <hip/hip_runtime.h>
#include <math.h>

#define N_NODES 50000
#define N_EDGES 800000
#define D_IN    128
#define H_DIM   256
#define L_LAYERS 3

// ---------------- CSR build ----------------

__global__ __launch_bounds__(256) void zero_kernel(int* __restrict__ counts,
                                                   int* __restrict__ cursor, int n) {
    int i = blockIdx.x * 256 + threadIdx.x;
    if (i < n) { counts[i] = 0; cursor[i] = 0; }
}

__global__ __launch_bounds__(256) void hist_kernel(const int* __restrict__ dst,
                                                   int* __restrict__ counts, int e_cnt) {
    int e = blockIdx.x * 256 + threadIdx.x;
    if (e < e_cnt) atomicAdd(&counts[dst[e]], 1);
}

// single-block exclusive scan over counts -> offsets, plus dinv = rsqrt(deg+1)
__global__ __launch_bounds__(1024) void scan_kernel(const int* __restrict__ counts,
                                                    int* __restrict__ offsets,
                                                    float* __restrict__ dinv, int n) {
    __shared__ int sums[1024];
    int t = threadIdx.x;
    int chunk = (n + 1023) / 1024;
    int lo = t * chunk;
    int hi = lo + chunk; if (hi > n) hi = n;
    int s = 0;
    for (int i = lo; i < hi; ++i) s += counts[i];
    sums[t] = s;
    __syncthreads();
    // Hillis-Steele inclusive scan
    for (int d = 1; d < 1024; d <<= 1) {
        int v = (t >= d) ? sums[t - d] : 0;
        __syncthreads();
        sums[t] += v;
        __syncthreads();
    }
    int pre = (t == 0) ? 0 : sums[t - 1];
    for (int i = lo; i < hi; ++i) {
        int c = counts[i];
        offsets[i] = pre;
        pre += c;
        dinv[i] = rsqrtf((float)(c + 1));   // +1 self-loop; always > 0
    }
    if (t == 1023) offsets[n] = pre;        // pre == total edge count here
}

__global__ __launch_bounds__(256) void fill_kernel(const int* __restrict__ src,
                                                   const int* __restrict__ dst,
                                                   const int* __restrict__ offsets,
                                                   int* __restrict__ cursor,
                                                   const float* __restrict__ dinv,
                                                   int* __restrict__ csr_src,
                                                   float* __restrict__ csr_w, int e_cnt) {
    int e = blockIdx.x * 256 + threadIdx.x;
    if (e < e_cnt) {
        int d = dst[e];
        int pos = offsets[d] + atomicAdd(&cursor[d], 1);
        int s = src[e];
        csr_src[pos] = s;
        csr_w[pos]   = dinv[s];
    }
}

// ---------------- aggregation: agg[v] = dinv[v]*(sum_e dinv[src]*h[src] + dinv[v]*h[v]) ----------------
// one wave per node; lane handles 4 columns (float4) of the 256-wide row

__global__ __launch_bounds__(256) void aggregate_kernel(const float* __restrict__ h,
                                                        const int* __restrict__ offsets,
                                                        const int* __restrict__ csr_src,
                                                        const float* __restrict__ csr_w,
                                                        const float* __restrict__ dinv,
                                                        float* __restrict__ out, int n) {
    int wave = threadIdx.x >> 6;
    int lane = threadIdx.x & 63;
    int v = blockIdx.x * 4 + wave;
    if (v >= n) return;
    int c = lane * 4;
    float dv = dinv[v];
    const float* hv = h + (size_t)v * H_DIM + c;
    float4 self = *(const float4*)hv;
    float4 acc;
    acc.x = dv * self.x; acc.y = dv * self.y; acc.z = dv * self.z; acc.w = dv * self.w;

    int e  = offsets[v];
    int e1 = offsets[v + 1];
    // unroll-2 for memory-level parallelism
    for (; e + 1 < e1; e += 2) {
        int   s0 = csr_src[e],   s1 = csr_src[e + 1];
        float w0 = csr_w[e],     w1 = csr_w[e + 1];
        float4 a = *(const float4*)(h + (size_t)s0 * H_DIM + c);
        float4 b = *(const float4*)(h + (size_t)s1 * H_DIM + c);
        acc.x += w0 * a.x + w1 * b.x;
        acc.y += w0 * a.y + w1 * b.y;
        acc.z += w0 * a.z + w1 * b.z;
        acc.w += w0 * a.w + w1 * b.w;
    }
    if (e < e1) {
        int   s0 = csr_src[e];
        float w0 = csr_w[e];
        float4 a = *(const float4*)(h + (size_t)s0 * H_DIM + c);
        acc.x += w0 * a.x; acc.y += w0 * a.y; acc.z += w0 * a.z; acc.w += w0 * a.w;
    }
    acc.x *= dv; acc.y *= dv; acc.z *= dv; acc.w *= dv;
    *(float4*)(out + (size_t)v * H_DIM + c) = acc;
}

// ---------------- fp32 GEMM: C[n,256] = act(A[n,K] @ W[K,256] + bias) ----------------
// block: 256 threads -> tile 32 rows x 256 cols; thread: 8 rows x 4 cols (32 acc)
// A-tile broadcast from LDS (wave-uniform float4 reads), W-tile staged in LDS.

#define GROWS 32
#define GKB   32

__global__ __launch_bounds__(256) void gemm_kernel(const float* __restrict__ A, int lda, int K,
                                                   const float* __restrict__ W,   // [K,256]
                                                   const float* __restrict__ bias,
                                                   float* __restrict__ C, int n, int relu) {
    __shared__ float As[GROWS][GKB];    // 4 KB
    __shared__ float Ws[GKB][H_DIM];    // 32 KB
    int t = threadIdx.x;
    int row0 = blockIdx.x * GROWS;
    int j4 = (t & 63) * 4;              // column (float4 base)
    int rg = (t >> 6) * 8;              // row-group base (0,8,16,24) — uniform per wave

    float4 acc[8];
#pragma unroll
    for (int r = 0; r < 8; ++r) acc[r] = make_float4(0.f, 0.f, 0.f, 0.f);

    for (int k0 = 0; k0 < K; k0 += GKB) {
        // stage A tile: 32x32 floats, one float4 per thread
        {
            int idx = t * 4;
            int r  = idx >> 5;
            int kk = idx & 31;
            int gr = row0 + r;
            float4 v = make_float4(0.f, 0.f, 0.f, 0.f);
            if (gr < n) v = *(const float4*)(A + (size_t)gr * lda + k0 + kk);
            *(float4*)&As[r][kk] = v;
        }
        // stage W tile: 32x256 floats, 8 float4 per thread
        {
#pragma unroll
            for (int i = 0; i < 8; ++i) {
                int idx = i * 256 + t;          // float4 index in tile
                int kk  = idx >> 6;             // 64 float4 per k-row
                int c4  = (idx & 63) * 4;
                *(float4*)&Ws[kk][c4] = *(const float4*)(W + (size_t)(k0 + kk) * H_DIM + c4);
            }
        }
        __syncthreads();
#pragma unroll
        for (int kk = 0; kk < GKB; kk += 4) {
            float4 w0 = *(const float4*)&Ws[kk + 0][j4];
            float4 w1 = *(const float4*)&Ws[kk + 1][j4];
            float4 w2 = *(const float4*)&Ws[kk + 2][j4];
            float4 w3 = *(const float4*)&Ws[kk + 3][j4];
#pragma unroll
            for (int r = 0; r < 8; ++r) {
                float4 a = *(const float4*)&As[rg + r][kk];
                acc[r].x += a.x * w0.x + a.y * w1.x + a.z * w2.x + a.w * w3.x;
                acc[r].y += a.x * w0.y + a.y * w1.y + a.z * w2.y + a.w * w3.y;
                acc[r].z += a.x * w0.z + a.y * w1.z + a.z * w2.z + a.w * w3.z;
                acc[r].w += a.x * w0.w + a.y * w1.w + a.z * w2.w + a.w * w3.w;
            }
        }
        __syncthreads();
    }

    float4 b = *(const float4*)(bias + j4);
#pragma unroll
    for (int r = 0; r < 8; ++r) {
        int gr = row0 + rg + r;
        if (gr < n) {
            float4 v;
            v.x = acc[r].x + b.x;
            v.y = acc[r].y + b.y;
            v.z = acc[r].z + b.z;
            v.w = acc[r].w + b.w;
            if (relu) {
                v.x = fmaxf(v.x, 0.f); v.y = fmaxf(v.y, 0.f);
                v.z = fmaxf(v.z, 0.f); v.w = fmaxf(v.w, 0.f);
            }
            *(float4*)(C + (size_t)gr * H_DIM + j4) = v;
        }
    }
}

// ---------------- launch ----------------

extern "C" void kernel_launch(void* const* d_in, const int* in_sizes, int n_in,
                              void* d_out, int out_size, void* d_ws, size_t ws_size,
                              hipStream_t stream) {
    const float* x     = (const float*)d_in[0];
    const int*   ei    = (const int*)d_in[1];
    // d_in[2] edge_attr unused by reference
    const float* W_enc = (const float*)d_in[3];
    const float* b_enc = (const float*)d_in[4];
    const float* W_g   = (const float*)d_in[5];
    const float* b_g   = (const float*)d_in[6];
    const float* W_out = (const float*)d_in[7];
    const float* b_out = (const float*)d_in[8];
    float* out = (float*)d_out;

    char* ws = (char*)d_ws;
    size_t off = 0;
    auto alloc = [&](size_t bytes) -> void* {
        void* p = ws + off;
        off = (off + bytes + 255) & ~(size_t)255;
        return p;
    };
    int*   counts  = (int*)alloc((size_t)N_NODES * 4);
    int*   offsets = (int*)alloc((size_t)(N_NODES + 1) * 4);
    int*   cursor  = (int*)alloc((size_t)N_NODES * 4);
    float* dinv    = (float*)alloc((size_t)N_NODES * 4);
    int*   csr_src = (int*)alloc((size_t)N_EDGES * 4);
    float* csr_w   = (float*)alloc((size_t)N_EDGES * 4);
    float* h       = (float*)alloc((size_t)N_NODES * H_DIM * 4);
    float* agg     = out;   // reuse output buffer as aggregation scratch

    const int* src = ei;             // edge_index[0]
    const int* dst = ei + N_EDGES;   // edge_index[1]

    zero_kernel<<<(N_NODES + 255) / 256, 256, 0, stream>>>(counts, cursor, N_NODES);
    hist_kernel<<<(N_EDGES + 255) / 256, 256, 0, stream>>>(dst, counts, N_EDGES);
    scan_kernel<<<1, 1024, 0, stream>>>(counts, offsets, dinv, N_NODES);
    fill_kernel<<<(N_EDGES + 255) / 256, 256, 0, stream>>>(src, dst, offsets, cursor, dinv,
                                                           csr_src, csr_w, N_EDGES);

    int gemm_grid = (N_NODES + GROWS - 1) / GROWS;
    // encoder: h = relu(x @ W_enc + b_enc)
    gemm_kernel<<<gemm_grid, 256, 0, stream>>>(x, D_IN, D_IN, W_enc, b_enc, h, N_NODES, 1);
    // 3 GCN layers: h = relu(aggregate(h) @ W_g[l] + b_g[l])
    for (int l = 0; l < L_LAYERS; ++l) {
        aggregate_kernel<<<N_NODES / 4, 256, 0, stream>>>(h, offsets, csr_src, csr_w, dinv,
                                                          agg, N_NODES);
        gemm_kernel<<<gemm_grid, 256, 0, stream>>>(agg, H_DIM, H_DIM,
                                                   W_g + (size_t)l * H_DIM * H_DIM,
                                                   b_g + (size_t)l * H_DIM, h, N_NODES, 1);
    }
    // output: out = h @ W_out + b_out (no relu)
    gemm_kernel<<<gemm_grid, 256, 0, stream>>>(h, H_DIM, H_DIM, W_out, b_out, out, N_NODES, 0);
}

// Round 2
// 819.741 us; speedup vs baseline: 1.8545x; 1.8545x over previous
//
#include <hip/hip_runtime.h>
#include <math.h>

#define N_NODES 50000
#define N_EDGES 800000
#define D_IN    128
#define H_DIM   256
#define L_LAYERS 3

typedef short     bf16x8 __attribute__((ext_vector_type(8)));
typedef float     f32x4  __attribute__((ext_vector_type(4)));

// ---------------- CSR build ----------------

__global__ __launch_bounds__(256) void zero_kernel(int* __restrict__ counts,
                                                   int* __restrict__ cursor, int n) {
    int i = blockIdx.x * 256 + threadIdx.x;
    if (i < n) { counts[i] = 0; cursor[i] = 0; }
}

__global__ __launch_bounds__(256) void hist_kernel(const int* __restrict__ dst,
                                                   int* __restrict__ counts, int e_cnt) {
    int e = blockIdx.x * 256 + threadIdx.x;
    if (e < e_cnt) atomicAdd(&counts[dst[e]], 1);
}

__global__ __launch_bounds__(1024) void scan_kernel(const int* __restrict__ counts,
                                                    int* __restrict__ offsets,
                                                    float* __restrict__ dinv, int n) {
    __shared__ int sums[1024];
    int t = threadIdx.x;
    int chunk = (n + 1023) / 1024;
    int lo = t * chunk;
    int hi = lo + chunk; if (hi > n) hi = n;
    int s = 0;
    for (int i = lo; i < hi; ++i) s += counts[i];
    sums[t] = s;
    __syncthreads();
    for (int d = 1; d < 1024; d <<= 1) {
        int v = (t >= d) ? sums[t - d] : 0;
        __syncthreads();
        sums[t] += v;
        __syncthreads();
    }
    int pre = (t == 0) ? 0 : sums[t - 1];
    for (int i = lo; i < hi; ++i) {
        int c = counts[i];
        offsets[i] = pre;
        pre += c;
        dinv[i] = rsqrtf((float)(c + 1));
    }
    if (t == 1023) offsets[n] = pre;
}

__global__ __launch_bounds__(256) void fill_kernel(const int* __restrict__ src,
                                                   const int* __restrict__ dst,
                                                   const int* __restrict__ offsets,
                                                   int* __restrict__ cursor,
                                                   const float* __restrict__ dinv,
                                                   int* __restrict__ csr_src,
                                                   float* __restrict__ csr_w, int e_cnt) {
    int e = blockIdx.x * 256 + threadIdx.x;
    if (e < e_cnt) {
        int d = dst[e];
        int pos = offsets[d] + atomicAdd(&cursor[d], 1);
        int s = src[e];
        csr_src[pos] = s;
        csr_w[pos]   = dinv[s];
    }
}

// ---------------- aggregation (unchanged this round) ----------------

__global__ __launch_bounds__(256) void aggregate_kernel(const float* __restrict__ h,
                                                        const int* __restrict__ offsets,
                                                        const int* __restrict__ csr_src,
                                                        const float* __restrict__ csr_w,
                                                        const float* __restrict__ dinv,
                                                        float* __restrict__ out, int n) {
    int wave = threadIdx.x >> 6;
    int lane = threadIdx.x & 63;
    int v = blockIdx.x * 4 + wave;
    if (v >= n) return;
    int c = lane * 4;
    float dv = dinv[v];
    float4 self = *(const float4*)(h + (size_t)v * H_DIM + c);
    float4 acc;
    acc.x = dv * self.x; acc.y = dv * self.y; acc.z = dv * self.z; acc.w = dv * self.w;

    int e  = offsets[v];
    int e1 = offsets[v + 1];
    for (; e + 1 < e1; e += 2) {
        int   s0 = csr_src[e],   s1 = csr_src[e + 1];
        float w0 = csr_w[e],     w1 = csr_w[e + 1];
        float4 a = *(const float4*)(h + (size_t)s0 * H_DIM + c);
        float4 b = *(const float4*)(h + (size_t)s1 * H_DIM + c);
        acc.x += w0 * a.x + w1 * b.x;
        acc.y += w0 * a.y + w1 * b.y;
        acc.z += w0 * a.z + w1 * b.z;
        acc.w += w0 * a.w + w1 * b.w;
    }
    if (e < e1) {
        int   s0 = csr_src[e];
        float w0 = csr_w[e];
        float4 a = *(const float4*)(h + (size_t)s0 * H_DIM + c);
        acc.x += w0 * a.x; acc.y += w0 * a.y; acc.z += w0 * a.z; acc.w += w0 * a.w;
    }
    acc.x *= dv; acc.y *= dv; acc.z *= dv; acc.w *= dv;
    *(float4*)(out + (size_t)v * H_DIM + c) = acc;
}

// ---------------- weight pre-convert: fp32 [K,256] -> frag-linear bf16 hi/lo ----------------
// Layout per 32-k chunk: [nt(16)][lane(64)][j(8)] where lane holds col n=nt*16+(lane&15),
// k = kc*32 + (lane>>4)*8 + j.  dst = base + (k>>5)*8192 + (n>>4)*512 + ((k&31)>>3)*128
//                                    + (n&15)*8 + (k&7)
// Segments in one flat buffer: enc [0,32768) K=128; W_g as one K=768 matrix [32768,229376);
// W_out [229376,294912).

#define WCONV_TOTAL 294912

__global__ __launch_bounds__(256) void wconv_kernel(const float* __restrict__ W_enc,
                                                    const float* __restrict__ W_g,
                                                    const float* __restrict__ W_out,
                                                    ushort* __restrict__ whi,
                                                    ushort* __restrict__ wlo) {
    int gid = blockIdx.x * 256 + threadIdx.x;
    if (gid >= WCONV_TOTAL) return;
    const float* src; int base, e;
    if (gid < 32768)       { src = W_enc; base = 0;      e = gid; }
    else if (gid < 229376) { src = W_g;   base = 32768;  e = gid - 32768; }
    else                   { src = W_out; base = 229376; e = gid - 229376; }
    int k = e >> 8;
    int n = e & 255;
    float x = src[e];
    unsigned u = __float_as_uint(x);
    ushort hb = (ushort)(u >> 16);
    float xhi = __uint_as_float(u & 0xFFFF0000u);
    float rem = x - xhi;
    ushort lb = (ushort)(__float_as_uint(rem) >> 16);
    int dst = base + (k >> 5) * 8192 + (n >> 4) * 512 + ((k & 31) >> 3) * 128
            + (n & 15) * 8 + (k & 7);
    whi[dst] = hb;
    wlo[dst] = lb;
}

// ---------------- split-bf16 MFMA GEMM: C[n,256] = act(A[n,K] @ W[K,256] + bias) --------
// block: 256 thr = 4 waves; tile M=64 x N=256; wave w -> cols [64w,64w+64)
// per wave: 4x4 grid of 16x16 tiles via v_mfma_f32_16x16x32_bf16, split hi/lo (3 MFMA/tile)

__global__ __launch_bounds__(256, 3) void mfma_gemm(const float* __restrict__ A, int K,
                                                    const ushort* __restrict__ Whi,
                                                    const ushort* __restrict__ Wlo,
                                                    const float* __restrict__ bias,
                                                    float* __restrict__ C, int n, int relu) {
    __shared__ ushort Ah[2048];   // [mt(4)][lane(64)][j(8)]
    __shared__ ushort Al[2048];
    __shared__ ushort Wh[8192];   // [nt(16)][lane(64)][j(8)]
    __shared__ ushort Wl[8192];

    int t = threadIdx.x;
    int w = t >> 6;
    int lane = t & 63;
    int row0 = blockIdx.x * 64;

    f32x4 acc[4][4];
#pragma unroll
    for (int mt = 0; mt < 4; ++mt)
#pragma unroll
        for (int c = 0; c < 4; ++c)
            acc[mt][c] = (f32x4)(0.0f);

    int ar = t >> 2;        // row 0..63 of A tile
    int ag = t & 3;         // k-octet 0..3
    int aoff = (ar >> 4) * 512 + ag * 128 + (ar & 15) * 8;   // ushort offset, 16B-aligned

    int nkc = K >> 5;
    for (int kc = 0; kc < nkc; ++kc) {
        // ---- stage A: load 8 fp32, split to bf16 hi/lo, 16B LDS writes ----
        float4 a0 = make_float4(0.f,0.f,0.f,0.f), a1 = a0;
        int grow = row0 + ar;
        if (grow < n) {
            const float* p = A + (size_t)grow * K + kc * 32 + ag * 8;
            a0 = *(const float4*)p;
            a1 = *(const float4*)(p + 4);
        }
        union { ushort s[8]; uint4 v; } uh, ul;
        float xs[8] = {a0.x, a0.y, a0.z, a0.w, a1.x, a1.y, a1.z, a1.w};
#pragma unroll
        for (int j = 0; j < 8; ++j) {
            unsigned u = __float_as_uint(xs[j]);
            uh.s[j] = (ushort)(u >> 16);
            float rem = xs[j] - __uint_as_float(u & 0xFFFF0000u);
            ul.s[j] = (ushort)(__float_as_uint(rem) >> 16);
        }
        *(uint4*)&Ah[aoff] = uh.v;
        *(uint4*)&Al[aoff] = ul.v;

        // ---- stage W hi/lo via async global->LDS (contiguous frag-linear copy) ----
        const ushort* gh = Whi + (size_t)kc * 8192;
        const ushort* gl = Wlo + (size_t)kc * 8192;
#pragma unroll
        for (int i = 0; i < 4; ++i) {
            int chunk = w * 4 + i;               // 16 x 1KB chunks
            __builtin_amdgcn_global_load_lds(
                (const __attribute__((address_space(1))) unsigned int*)(gh + chunk * 512 + lane * 8),
                (__attribute__((address_space(3))) unsigned int*)(&Wh[chunk * 512]),
                16, 0, 0);
            __builtin_amdgcn_global_load_lds(
                (const __attribute__((address_space(1))) unsigned int*)(gl + chunk * 512 + lane * 8),
                (__attribute__((address_space(3))) unsigned int*)(&Wl[chunk * 512]),
                16, 0, 0);
        }
        __syncthreads();

        // ---- fragments + MFMA ----
        bf16x8 ahf[4], alf[4];
#pragma unroll
        for (int mt = 0; mt < 4; ++mt) {
            ahf[mt] = *(const bf16x8*)&Ah[(mt * 64 + lane) * 8];
            alf[mt] = *(const bf16x8*)&Al[(mt * 64 + lane) * 8];
        }
#pragma unroll
        for (int c = 0; c < 4; ++c) {
            int nt = w * 4 + c;
            bf16x8 bh = *(const bf16x8*)&Wh[(nt * 64 + lane) * 8];
            bf16x8 bl = *(const bf16x8*)&Wl[(nt * 64 + lane) * 8];
#pragma unroll
            for (int mt = 0; mt < 4; ++mt) {
                acc[mt][c] = __builtin_amdgcn_mfma_f32_16x16x32_bf16(ahf[mt], bh, acc[mt][c], 0, 0, 0);
                acc[mt][c] = __builtin_amdgcn_mfma_f32_16x16x32_bf16(alf[mt], bh, acc[mt][c], 0, 0, 0);
                acc[mt][c] = __builtin_amdgcn_mfma_f32_16x16x32_bf16(ahf[mt], bl, acc[mt][c], 0, 0, 0);
            }
        }
        __syncthreads();
    }

    // ---- epilogue: C/D layout col=lane&15, row=(lane>>4)*4+reg ----
    int colq = lane & 15;
    int rowq = (lane >> 4) * 4;
#pragma unroll
    for (int c = 0; c < 4; ++c) {
        int col = w * 64 + c * 16 + colq;
        float b = bias[col];
#pragma unroll
        for (int mt = 0; mt < 4; ++mt) {
            int rb = row0 + mt * 16 + rowq;
#pragma unroll
            for (int r = 0; r < 4; ++r) {
                int row = rb + r;
                if (row < n) {
                    float v = acc[mt][c][r] + b;
                    if (relu) v = fmaxf(v, 0.f);
                    C[(size_t)row * H_DIM + col] = v;
                }
            }
        }
    }
}

// ---------------- launch ----------------

extern "C" void kernel_launch(void* const* d_in, const int* in_sizes, int n_in,
                              void* d_out, int out_size, void* d_ws, size_t ws_size,
                              hipStream_t stream) {
    const float* x     = (const float*)d_in[0];
    const int*   ei    = (const int*)d_in[1];
    const float* W_enc = (const float*)d_in[3];
    const float* b_enc = (const float*)d_in[4];
    const float* W_g   = (const float*)d_in[5];
    const float* b_g   = (const float*)d_in[6];
    const float* W_out = (const float*)d_in[7];
    const float* b_out = (const float*)d_in[8];
    float* out = (float*)d_out;

    char* ws = (char*)d_ws;
    size_t off = 0;
    auto alloc = [&](size_t bytes) -> void* {
        void* p = ws + off;
        off = (off + bytes + 255) & ~(size_t)255;
        return p;
    };
    int*    counts  = (int*)alloc((size_t)N_NODES * 4);
    int*    offsets = (int*)alloc((size_t)(N_NODES + 1) * 4);
    int*    cursor  = (int*)alloc((size_t)N_NODES * 4);
    float*  dinv    = (float*)alloc((size_t)N_NODES * 4);
    int*    csr_src = (int*)alloc((size_t)N_EDGES * 4);
    float*  csr_w   = (float*)alloc((size_t)N_EDGES * 4);
    float*  h       = (float*)alloc((size_t)N_NODES * H_DIM * 4);
    ushort* whi     = (ushort*)alloc((size_t)WCONV_TOTAL * 2);
    ushort* wlo     = (ushort*)alloc((size_t)WCONV_TOTAL * 2);
    float*  agg     = out;   // reuse output buffer as aggregation scratch

    const int* src = ei;
    const int* dst = ei + N_EDGES;

    zero_kernel<<<(N_NODES + 255) / 256, 256, 0, stream>>>(counts, cursor, N_NODES);
    hist_kernel<<<(N_EDGES + 255) / 256, 256, 0, stream>>>(dst, counts, N_EDGES);
    scan_kernel<<<1, 1024, 0, stream>>>(counts, offsets, dinv, N_NODES);
    fill_kernel<<<(N_EDGES + 255) / 256, 256, 0, stream>>>(src, dst, offsets, cursor, dinv,
                                                           csr_src, csr_w, N_EDGES);
    wconv_kernel<<<(WCONV_TOTAL + 255) / 256, 256, 0, stream>>>(W_enc, W_g, W_out, whi, wlo);

    int gemm_grid = (N_NODES + 63) / 64;
    // encoder: h = relu(x @ W_enc + b_enc)   (K=128, chunks start at whi+0)
    mfma_gemm<<<gemm_grid, 256, 0, stream>>>(x, D_IN, whi, wlo, b_enc, h, N_NODES, 1);
    // 3 GCN layers
    for (int l = 0; l < L_LAYERS; ++l) {
        aggregate_kernel<<<N_NODES / 4, 256, 0, stream>>>(h, offsets, csr_src, csr_w, dinv,
                                                          agg, N_NODES);
        mfma_gemm<<<gemm_grid, 256, 0, stream>>>(agg, H_DIM,
                                                 whi + 32768 + (size_t)l * 65536,
                                                 wlo + 32768 + (size_t)l * 65536,
                                                 b_g + (size_t)l * H_DIM, h, N_NODES, 1);
    }
    // output head (no relu)
    mfma_gemm<<<gemm_grid, 256, 0, stream>>>(h, H_DIM, whi + 229376, wlo + 229376,
                                             b_out, out, N_NODES, 0);
}